// Round 4
// baseline (69.553 us; speedup 1.0000x reference)
//
#include <hip/hip_runtime.h>
#include <hip/hip_bf16.h>

#define B_ 256
#define R_ 36
#define T_ 64
#define D_ 1024

// XOR swizzles for LDS tiles
#define SWZ64(k, c) ((c) ^ ((((k) >> 4) & 3) << 4))  // 64-wide tiles (sims)
#define SWZ32(k, b) ((b) ^ ((((k) >> 3) & 3) << 3))  // 32-wide tiles (sims)
#define SWZA(k, c)  ((c) ^ ((((k) >> 2) & 3) << 4))  // gemm A tile (64-wide)

__device__ __forceinline__ float lrelu(float x) { return x >= 0.0f ? x : 0.1f * x; }

// block-wide sum over 256 threads (4 waves)
__device__ __forceinline__ float block_sum(float v, float* sred) {
#pragma unroll
  for (int off = 32; off > 0; off >>= 1) v += __shfl_down(v, off, 64);
  int w = threadIdx.x >> 6;
  if ((threadIdx.x & 63) == 0) sred[w] = v;
  __syncthreads();
  float r = sred[0] + sred[1] + sred[2] + sred[3];
  __syncthreads();
  return r;
}

// ---- fused input streaming, float4 loads, 512 threads ----
// blocks 0..255: cap row b; blocks 256..511: img row b.
// thread: rp = row parity, dq = float4 index over D; LDS combine of the two parities.
__global__ __launch_bounds__(512) void input_kernel(const float* __restrict__ cap,
    const float* __restrict__ img, const int* __restrict__ lens,
    float* __restrict__ cap_mean, float* __restrict__ rowsum, float* __restrict__ rowss) {
  __shared__ float4 redA[256], redB[256];
  int bid = blockIdx.x;
  int t = threadIdx.x;
  int rp = t >> 8, dq = t & 255;
  if (bid < 256) {
    int b = bid;
    int len = lens[b];
    const float4* src = reinterpret_cast<const float4*>(cap) + (size_t)b * (T_ * D_ / 4) + dq;
    float4 s2 = {0, 0, 0, 0}, sm = {0, 0, 0, 0};
#pragma unroll 8
    for (int it = 0; it < 32; ++it) {
      int tt = it * 2 + rp;
      float4 v = src[(size_t)tt * 256];
      float y0 = lrelu(v.x), y1 = lrelu(v.y), y2 = lrelu(v.z), y3 = lrelu(v.w);
      s2.x += y0 * y0; s2.y += y1 * y1; s2.z += y2 * y2; s2.w += y3 * y3;
      bool in = tt < len;
      sm.x += in ? y0 : 0.0f; sm.y += in ? y1 : 0.0f;
      sm.z += in ? y2 : 0.0f; sm.w += in ? y3 : 0.0f;
    }
    if (rp) { redA[dq] = s2; redB[dq] = sm; }
    __syncthreads();
    if (!rp) {
      float4 o2 = redA[dq], om = redB[dq];
      s2.x += o2.x; s2.y += o2.y; s2.z += o2.z; s2.w += o2.w;
      sm.x += om.x; sm.y += om.y; sm.z += om.z; sm.w += om.w;
      float il = 1.0f / (float)len;
      float4 cm;
      cm.x = sm.x / (sqrtf(s2.x) + 1e-8f) * il;
      cm.y = sm.y / (sqrtf(s2.y) + 1e-8f) * il;
      cm.z = sm.z / (sqrtf(s2.z) + 1e-8f) * il;
      cm.w = sm.w / (sqrtf(s2.w) + 1e-8f) * il;
      reinterpret_cast<float4*>(cap_mean)[(size_t)b * 256 + dq] = cm;
    }
  } else {
    int b = bid - 256;
    const float4* src = reinterpret_cast<const float4*>(img) + (size_t)b * (R_ * D_ / 4) + dq;
    float4 s1 = {0, 0, 0, 0}, s2 = {0, 0, 0, 0};
#pragma unroll 6
    for (int it = 0; it < 18; ++it) {
      int r = it * 2 + rp;
      float4 v = src[(size_t)r * 256];
      float y0 = lrelu(v.x), y1 = lrelu(v.y), y2 = lrelu(v.z), y3 = lrelu(v.w);
      s1.x += y0; s1.y += y1; s1.z += y2; s1.w += y3;
      s2.x += y0 * y0; s2.y += y1 * y1; s2.z += y2 * y2; s2.w += y3 * y3;
    }
    if (rp) { redA[dq] = s1; redB[dq] = s2; }
    __syncthreads();
    if (!rp) {
      float4 o1 = redA[dq], o2 = redB[dq];
      s1.x += o1.x; s1.y += o1.y; s1.z += o1.z; s1.w += o1.w;
      s2.x += o2.x; s2.y += o2.y; s2.z += o2.z; s2.w += o2.w;
      float n0 = sqrtf(s2.x) + 1e-8f, n1 = sqrtf(s2.y) + 1e-8f;
      float n2 = sqrtf(s2.z) + 1e-8f, n3 = sqrtf(s2.w) + 1e-8f;
      float4 rs, ss;
      rs.x = s1.x / n0; rs.y = s1.y / n1; rs.z = s1.z / n2; rs.w = s1.w / n3;
      ss.x = s2.x / (n0 * n0); ss.y = s2.y / (n1 * n1);
      ss.z = s2.z / (n2 * n2); ss.w = s2.w / (n3 * n3);
      reinterpret_cast<float4*>(rowsum)[(size_t)b * 256 + dq] = rs;
      reinterpret_cast<float4*>(rowss)[(size_t)b * 256 + dq] = ss;
    }
  }
}

// ---- fused: params GEMM (blocks 0..511) + BN stats (blocks 512..527) ----
// GEMM: Ppart[kz] = cap_mean @ fc_w^T slab (M=256,N=2048,K=1024), split-K=8,
//   tile 64c x 128n, K-chunk 128, BK=16, 4x8 acc/thread (32 FMA : 3 b128)
// stats: g[d] = bn_w/sqrt(var+eps), h[d] = mu*g - bn_b
__global__ __launch_bounds__(256) void gemm_stats_kernel(
    const float* __restrict__ cap_mean, const float* __restrict__ fc_w,
    const float* __restrict__ rowsum, const float* __restrict__ rowss,
    const float* __restrict__ bn_w, const float* __restrict__ bn_b,
    float* __restrict__ Ppart, float* __restrict__ g, float* __restrict__ h) {
  __shared__ float As[16][64];   // [k][c], SWZA-swizzled
  __shared__ float Bs[16][128];  // [k][n]
  __shared__ float s1s[4][64], s2s[4][64];
  int bid = blockIdx.x;
  int t = threadIdx.x;
  if (bid < 512) {
    int nt = bid & 15, ct = (bid >> 4) & 3, kz = bid >> 6;
    int tr = t >> 4, tc = t & 15;            // out: c-rows tr*4.., n-cols tc*8..
    int ca = t >> 2, ka = (t & 3) << 2;      // A staging: row ca, 4 k from ka
    int nb = t >> 1, kb0 = (t & 1) << 3;     // B staging: row nb, 8 k from kb0
    const float* arow = cap_mean + (size_t)(ct * 64 + ca) * D_ + kz * 128;
    const float* brow = fc_w + (size_t)(nt * 128 + nb) * D_ + kz * 128;
    float acc[4][8] = {};
    int sca = SWZA(ka, ca);  // (ka..ka+3)>>2 constant -> swizzled col constant
    for (int kb = 0; kb < 128; kb += 16) {
      float4 av = *(const float4*)&arow[kb + ka];
      float4 b0 = *(const float4*)&brow[kb + kb0];
      float4 b1 = *(const float4*)&brow[kb + kb0 + 4];
      __syncthreads();  // previous iter's readers done
      As[ka + 0][sca] = av.x; As[ka + 1][sca] = av.y;
      As[ka + 2][sca] = av.z; As[ka + 3][sca] = av.w;
      Bs[kb0 + 0][nb] = b0.x; Bs[kb0 + 1][nb] = b0.y; Bs[kb0 + 2][nb] = b0.z; Bs[kb0 + 3][nb] = b0.w;
      Bs[kb0 + 4][nb] = b1.x; Bs[kb0 + 5][nb] = b1.y; Bs[kb0 + 6][nb] = b1.z; Bs[kb0 + 7][nb] = b1.w;
      __syncthreads();
#pragma unroll
      for (int kk = 0; kk < 16; ++kk) {
        float4 a = *(const float4*)&As[kk][SWZA(kk, tr * 4)];
        float4 q0 = *(const float4*)&Bs[kk][tc * 8];
        float4 q1 = *(const float4*)&Bs[kk][tc * 8 + 4];
        acc[0][0] += a.x * q0.x; acc[0][1] += a.x * q0.y; acc[0][2] += a.x * q0.z; acc[0][3] += a.x * q0.w;
        acc[0][4] += a.x * q1.x; acc[0][5] += a.x * q1.y; acc[0][6] += a.x * q1.z; acc[0][7] += a.x * q1.w;
        acc[1][0] += a.y * q0.x; acc[1][1] += a.y * q0.y; acc[1][2] += a.y * q0.z; acc[1][3] += a.y * q0.w;
        acc[1][4] += a.y * q1.x; acc[1][5] += a.y * q1.y; acc[1][6] += a.y * q1.z; acc[1][7] += a.y * q1.w;
        acc[2][0] += a.z * q0.x; acc[2][1] += a.z * q0.y; acc[2][2] += a.z * q0.z; acc[2][3] += a.z * q0.w;
        acc[2][4] += a.z * q1.x; acc[2][5] += a.z * q1.y; acc[2][6] += a.z * q1.z; acc[2][7] += a.z * q1.w;
        acc[3][0] += a.w * q0.x; acc[3][1] += a.w * q0.y; acc[3][2] += a.w * q0.z; acc[3][3] += a.w * q0.w;
        acc[3][4] += a.w * q1.x; acc[3][5] += a.w * q1.y; acc[3][6] += a.w * q1.z; acc[3][7] += a.w * q1.w;
      }
    }
    int c = ct * 64 + tr * 4;
    int n = nt * 128 + tc * 8;
#pragma unroll
    for (int i = 0; i < 4; ++i) {
      size_t o = ((size_t)kz * 256 + c + i) * 2048 + n;
      *(float4*)&Ppart[o] = make_float4(acc[i][0], acc[i][1], acc[i][2], acc[i][3]);
      *(float4*)&Ppart[o + 4] = make_float4(acc[i][4], acc[i][5], acc[i][6], acc[i][7]);
    }
  } else {
    int sb = bid - 512;
    int dl = t & 63;
    int d = sb * 64 + dl;
    int bg = t >> 6;
    float cs = 0.0f, c2 = 0.0f;
    for (int b = bg * 64; b < bg * 64 + 64; ++b) {
      cs += rowsum[(size_t)b * D_ + d];
      c2 += rowss[(size_t)b * D_ + d];
    }
    s1s[bg][dl] = cs;
    s2s[bg][dl] = c2;
    __syncthreads();
    if (t < 64) {
      cs = s1s[0][dl] + s1s[1][dl] + s1s[2][dl] + s1s[3][dl];
      c2 = s2s[0][dl] + s2s[1][dl] + s2s[2][dl] + s2s[3][dl];
      const float inv = 1.0f / (float)(B_ * R_);
      float m = cs * inv, ex2 = c2 * inv;
      float var = ex2 - m * m;
      float gg = bn_w[d] / sqrtf(var + 1e-5f);
      g[d] = gg;
      h[d] = m * gg - bn_b[d];
    }
  }
}

// ---- fused: reduce split-K partials + fc_b -> params; per-c scalars ----
__global__ __launch_bounds__(256) void reduce_scal_kernel(const float* __restrict__ Ppart,
    const float* __restrict__ fc_b, const float* __restrict__ cap_mean,
    float* __restrict__ params, float* __restrict__ rawC, float* __restrict__ BBc,
    float* __restrict__ rn) {
  __shared__ float sred[4], sred2[4], sred3[4];
  int c = blockIdx.x, t = threadIdx.x;
  float4 p0 = reinterpret_cast<const float4*>(fc_b)[2 * t];
  float4 p1 = reinterpret_cast<const float4*>(fc_b)[2 * t + 1];
#pragma unroll
  for (int kz = 0; kz < 8; ++kz) {
    size_t base4 = ((size_t)kz * 256 + c) * 512;
    float4 q0 = reinterpret_cast<const float4*>(Ppart)[base4 + 2 * t];
    float4 q1 = reinterpret_cast<const float4*>(Ppart)[base4 + 2 * t + 1];
    p0.x += q0.x; p0.y += q0.y; p0.z += q0.z; p0.w += q0.w;
    p1.x += q1.x; p1.y += q1.y; p1.z += q1.z; p1.w += q1.w;
  }
  reinterpret_cast<float4*>(params)[(size_t)c * 512 + 2 * t] = p0;
  reinterpret_cast<float4*>(params)[(size_t)c * 512 + 2 * t + 1] = p1;
  float4 cm = reinterpret_cast<const float4*>(cap_mean)[(size_t)c * 256 + t];
  float sBc = p0.y * cm.x + p0.w * cm.y + p1.y * cm.z + p1.w * cm.w;
  float sB2 = p0.y * p0.y + p0.w * p0.w + p1.y * p1.y + p1.w * p1.w;
  float scm = cm.x * cm.x + cm.y * cm.y + cm.z * cm.z + cm.w * cm.w;
  float a = block_sum(sBc, sred);
  float bsum = block_sum(sB2, sred2);
  float cq = block_sum(scm, sred3);
  if (t == 0) {
    rawC[c] = a;
    BBc[c] = bsum;
    rn[c] = 1.0f / (sqrtf(cq) + 1e-8f);
  }
}

// ---- fused 3-GEMM for sims numerator/denominator, split-K=16 ----
// grid (8 bt, 4 ct, 16 kz); tile 32b x 64c, K-chunk 64; base computed on the fly
__global__ __launch_bounds__(256) void sims_kernel(const float* __restrict__ rowsum,
    const float* __restrict__ g, const float* __restrict__ h,
    const float* __restrict__ params, const float* __restrict__ cap_mean,
    float* __restrict__ Npart, float* __restrict__ Qpart) {
  __shared__ float Tb[64][32];
  __shared__ float Tacv[64][64];
  __shared__ float Ta2[64][64];
  __shared__ float Tab[64][64];
  int t = threadIdx.x;
  int bt = blockIdx.x, ct = blockIdx.y, kz = blockIdx.z;
  int k0 = kz * 64;
  int tr = t >> 4, tc = t & 15;
  int bb = t >> 3, kb = (t & 7) << 3;   // Tb staging
  int cc = t >> 2, dc = (t & 3) << 4;   // T* staging
  const float* prow = params + (size_t)(ct * 64 + cc) * 2048 + 2 * k0;
  const float* cmrow = cap_mean + (size_t)(ct * 64 + cc) * 1024 + k0;
  const float* rsrow = rowsum + (size_t)(bt * 32 + bb) * 1024 + k0;
  const float invR = 1.0f / (float)R_;
  // stage Tb[k][b] = base (transposed, swizzled): base = rs*invR*g - h
  {
    float4 v0 = *(const float4*)&rsrow[kb];
    float4 v1 = *(const float4*)&rsrow[kb + 4];
    float4 g0 = *(const float4*)&g[k0 + kb];
    float4 g1 = *(const float4*)&g[k0 + kb + 4];
    float4 h0 = *(const float4*)&h[k0 + kb];
    float4 h1 = *(const float4*)&h[k0 + kb + 4];
    int sb = SWZ32(kb, bb);
    Tb[kb + 0][sb] = v0.x * invR * g0.x - h0.x;
    Tb[kb + 1][sb] = v0.y * invR * g0.y - h0.y;
    Tb[kb + 2][sb] = v0.z * invR * g0.z - h0.z;
    Tb[kb + 3][sb] = v0.w * invR * g0.w - h0.w;
    Tb[kb + 4][sb] = v1.x * invR * g1.x - h1.x;
    Tb[kb + 5][sb] = v1.y * invR * g1.y - h1.y;
    Tb[kb + 6][sb] = v1.z * invR * g1.z - h1.z;
    Tb[kb + 7][sb] = v1.w * invR * g1.w - h1.w;
  }
  // stage Tacv/Ta2/Tab [d][c] (swizzled); rn folded into final kernel
  int sc = SWZ64(dc, cc);
#pragma unroll
  for (int j = 0; j < 16; j += 4) {
    int d = dc + j;
    float4 p0 = *(const float4*)&prow[2 * d];
    float4 p1 = *(const float4*)&prow[2 * d + 4];
    float4 cm = *(const float4*)&cmrow[d];
    Tacv[d + 0][sc] = p0.x * cm.x; Ta2[d + 0][sc] = p0.x * p0.x; Tab[d + 0][sc] = 2.f * p0.x * p0.y;
    Tacv[d + 1][sc] = p0.z * cm.y; Ta2[d + 1][sc] = p0.z * p0.z; Tab[d + 1][sc] = 2.f * p0.z * p0.w;
    Tacv[d + 2][sc] = p1.x * cm.z; Ta2[d + 2][sc] = p1.x * p1.x; Tab[d + 2][sc] = 2.f * p1.x * p1.y;
    Tacv[d + 3][sc] = p1.z * cm.w; Ta2[d + 3][sc] = p1.z * p1.z; Tab[d + 3][sc] = 2.f * p1.z * p1.w;
  }
  __syncthreads();
  float accN[2][4] = {};
  float accQ[2][4] = {};
#pragma unroll 8
  for (int kk = 0; kk < 64; ++kk) {
    float2 bv = *(const float2*)&Tb[kk][SWZ32(kk, tr * 2)];
    float4 acv = *(const float4*)&Tacv[kk][SWZ64(kk, tc * 4)];
    float4 a2v = *(const float4*)&Ta2[kk][SWZ64(kk, tc * 4)];
    float4 abv = *(const float4*)&Tab[kk][SWZ64(kk, tc * 4)];
    float b0 = bv.x, b1 = bv.y;
    float q0 = b0 * b0, q1 = b1 * b1;
    accN[0][0] += b0 * acv.x; accN[0][1] += b0 * acv.y; accN[0][2] += b0 * acv.z; accN[0][3] += b0 * acv.w;
    accN[1][0] += b1 * acv.x; accN[1][1] += b1 * acv.y; accN[1][2] += b1 * acv.z; accN[1][3] += b1 * acv.w;
    accQ[0][0] += q0 * a2v.x; accQ[0][1] += q0 * a2v.y; accQ[0][2] += q0 * a2v.z; accQ[0][3] += q0 * a2v.w;
    accQ[1][0] += q1 * a2v.x; accQ[1][1] += q1 * a2v.y; accQ[1][2] += q1 * a2v.z; accQ[1][3] += q1 * a2v.w;
    accQ[0][0] += b0 * abv.x; accQ[0][1] += b0 * abv.y; accQ[0][2] += b0 * abv.z; accQ[0][3] += b0 * abv.w;
    accQ[1][0] += b1 * abv.x; accQ[1][1] += b1 * abv.y; accQ[1][2] += b1 * abv.z; accQ[1][3] += b1 * abv.w;
  }
  int br = bt * 32 + tr * 2;
  int c = ct * 64 + tc * 4;
#pragma unroll
  for (int i = 0; i < 2; ++i) {
    size_t o = ((size_t)kz * 256 + br + i) * 256 + c;
    *(float4*)&Npart[o] = make_float4(accN[i][0], accN[i][1], accN[i][2], accN[i][3]);
    *(float4*)&Qpart[o] = make_float4(accQ[i][0], accQ[i][1], accQ[i][2], accQ[i][3]);
  }
}

// ---- combine split-K partials, apply per-c constants + rn, normalize ----
__global__ __launch_bounds__(256) void final_kernel(const float* __restrict__ Npart,
    const float* __restrict__ Qpart, const float* __restrict__ rawC,
    const float* __restrict__ BBc, const float* __restrict__ rn, float* __restrict__ out) {
  int b = blockIdx.x, c = threadIdx.x;
  float N = rawC[c], Q = BBc[c];
#pragma unroll
  for (int kz = 0; kz < 16; ++kz) {
    size_t o = ((size_t)kz * 256 + b) * 256 + c;
    N += Npart[o];
    Q += Qpart[o];
  }
  out[b * 256 + c] = N * rn[c] / (sqrtf(Q) + 1e-8f);
}

extern "C" void kernel_launch(void* const* d_in, const int* in_sizes, int n_in,
                              void* d_out, int out_size, void* d_ws, size_t ws_size,
                              hipStream_t stream) {
  const float* img = (const float*)d_in[0];
  const float* cap = (const float*)d_in[1];
  const int* lens = (const int*)d_in[2];
  const float* fc_w = (const float*)d_in[3];
  const float* fc_b = (const float*)d_in[4];
  const float* bn_w = (const float*)d_in[5];
  const float* bn_b = (const float*)d_in[6];
  float* out = (float*)d_out;
  float* ws = (float*)d_ws;

  float* cap_mean = ws;                //  262144
  float* rowsum   = ws + 262144;       //  262144
  float* rowss    = ws + 524288;       //  262144
  float* g        = ws + 786432;       //    1024
  float* h        = ws + 787456;       //    1024
  float* params   = ws + 788480;       //  524288
  float* rawC     = ws + 1312768;      //     256
  float* BBc      = ws + 1313024;      //     256
  float* rn       = ws + 1313280;      //     256
  float* region   = ws + 1313536;      // shared: Ppart (8*524288) then Npart/Qpart
  float* Ppart    = region;            // 4194304 floats
  float* Npart    = region;            // 16 * 65536
  float* Qpart    = region + 1048576;  // 16 * 65536   total ws ~22 MB (<268 MB)

  input_kernel<<<512, 512, 0, stream>>>(cap, img, lens, cap_mean, rowsum, rowss);
  gemm_stats_kernel<<<528, 256, 0, stream>>>(cap_mean, fc_w, rowsum, rowss,
                                             bn_w, bn_b, Ppart, g, h);
  reduce_scal_kernel<<<256, 256, 0, stream>>>(Ppart, fc_b, cap_mean, params,
                                              rawC, BBc, rn);
  sims_kernel<<<dim3(8, 4, 16), 256, 0, stream>>>(rowsum, g, h, params, cap_mean,
                                                  Npart, Qpart);
  final_kernel<<<256, 256, 0, stream>>>(Npart, Qpart, rawC, BBc, rn, out);
}

// Round 6
// 65.055 us; speedup vs baseline: 1.0691x; 1.0691x over previous
//
#include <hip/hip_runtime.h>
#include <hip/hip_bf16.h>

#define B_ 256
#define R_ 36
#define T_ 64
#define D_ 1024

// XOR swizzles: make transposing scalar LDS stores and b128 reads <=2-way
#define SWZ64(k, c) ((c) ^ ((((k) >> 4) & 3) << 4))  // 64-wide tiles
#define SWZ32(k, b) ((b) ^ ((((k) >> 3) & 3) << 3))  // 32-wide tiles

__device__ __forceinline__ float lrelu(float x) { return x >= 0.0f ? x : 0.1f * x; }

// block-wide sum over 256 threads (4 waves)
__device__ __forceinline__ float block_sum(float v, float* sred) {
#pragma unroll
  for (int off = 32; off > 0; off >>= 1) v += __shfl_down(v, off, 64);
  int w = threadIdx.x >> 6;
  if ((threadIdx.x & 63) == 0) sred[w] = v;
  __syncthreads();
  float r = sred[0] + sred[1] + sred[2] + sred[3];
  __syncthreads();
  return r;
}

// ---- fused input streaming: float4 loads, 1024 blocks x 256 threads ----
// blocks 0..511: cap (b = bid>>1, half = bid&1 covers 512 d's); 512..1023: img.
// rp = row parity (t>>7), dq = float4 idx within half (t&127); LDS parity combine.
__global__ __launch_bounds__(256) void input_kernel(const float* __restrict__ cap,
    const float* __restrict__ img, const int* __restrict__ lens,
    float* __restrict__ cap_mean, float* __restrict__ rowsum, float* __restrict__ rowss) {
  __shared__ float4 redA[128], redB[128];
  int bid = blockIdx.x, t = threadIdx.x;
  int rp = t >> 7, dq = t & 127;
  if (bid < 512) {
    int b = bid >> 1, half = bid & 1;
    int len = lens[b];
    const float4* src = reinterpret_cast<const float4*>(cap) +
                        (size_t)b * (T_ * D_ / 4) + half * 128 + dq;
    float4 s2 = {0, 0, 0, 0}, sm = {0, 0, 0, 0};
#pragma unroll 4
    for (int it = 0; it < 32; ++it) {
      int tt = it * 2 + rp;
      float4 v = src[(size_t)tt * 256];
      float y0 = lrelu(v.x), y1 = lrelu(v.y), y2 = lrelu(v.z), y3 = lrelu(v.w);
      s2.x += y0 * y0; s2.y += y1 * y1; s2.z += y2 * y2; s2.w += y3 * y3;
      bool in = tt < len;
      sm.x += in ? y0 : 0.0f; sm.y += in ? y1 : 0.0f;
      sm.z += in ? y2 : 0.0f; sm.w += in ? y3 : 0.0f;
    }
    if (rp) { redA[dq] = s2; redB[dq] = sm; }
    __syncthreads();
    if (!rp) {
      float4 o2 = redA[dq], om = redB[dq];
      s2.x += o2.x; s2.y += o2.y; s2.z += o2.z; s2.w += o2.w;
      sm.x += om.x; sm.y += om.y; sm.z += om.z; sm.w += om.w;
      float il = 1.0f / (float)len;
      float4 cm;
      cm.x = sm.x / (sqrtf(s2.x) + 1e-8f) * il;
      cm.y = sm.y / (sqrtf(s2.y) + 1e-8f) * il;
      cm.z = sm.z / (sqrtf(s2.z) + 1e-8f) * il;
      cm.w = sm.w / (sqrtf(s2.w) + 1e-8f) * il;
      reinterpret_cast<float4*>(cap_mean)[(size_t)b * 256 + half * 128 + dq] = cm;
    }
  } else {
    int bb = bid - 512;
    int b = bb >> 1, half = bb & 1;
    const float4* src = reinterpret_cast<const float4*>(img) +
                        (size_t)b * (R_ * D_ / 4) + half * 128 + dq;
    float4 s1 = {0, 0, 0, 0}, s2 = {0, 0, 0, 0};
#pragma unroll 4
    for (int it = 0; it < 18; ++it) {
      int r = it * 2 + rp;
      float4 v = src[(size_t)r * 256];
      float y0 = lrelu(v.x), y1 = lrelu(v.y), y2 = lrelu(v.z), y3 = lrelu(v.w);
      s1.x += y0; s1.y += y1; s1.z += y2; s1.w += y3;
      s2.x += y0 * y0; s2.y += y1 * y1; s2.z += y2 * y2; s2.w += y3 * y3;
    }
    if (rp) { redA[dq] = s1; redB[dq] = s2; }
    __syncthreads();
    if (!rp) {
      float4 o1 = redA[dq], o2 = redB[dq];
      s1.x += o1.x; s1.y += o1.y; s1.z += o1.z; s1.w += o1.w;
      s2.x += o2.x; s2.y += o2.y; s2.z += o2.z; s2.w += o2.w;
      float n0 = sqrtf(s2.x) + 1e-8f, n1 = sqrtf(s2.y) + 1e-8f;
      float n2 = sqrtf(s2.z) + 1e-8f, n3 = sqrtf(s2.w) + 1e-8f;
      float4 rs, ss;
      rs.x = s1.x / n0; rs.y = s1.y / n1; rs.z = s1.z / n2; rs.w = s1.w / n3;
      ss.x = s2.x / (n0 * n0); ss.y = s2.y / (n1 * n1);
      ss.z = s2.z / (n2 * n2); ss.w = s2.w / (n3 * n3);
      reinterpret_cast<float4*>(rowsum)[(size_t)b * 256 + half * 128 + dq] = rs;
      reinterpret_cast<float4*>(rowss)[(size_t)b * 256 + half * 128 + dq] = ss;
    }
  }
}

// ---- fused: params GEMM (blocks 0..511) + BN stats (blocks 512..527) ----
// GEMM: params = cap_mean @ fc_w^T (M=256,N=2048,K=1024), split-K=4,
//   tile 64c x 64n, K-chunk 256, BK=32, k-major swizzled LDS, 4x4 acc/thread
// stats: g[d] = bn_w/sqrt(var+eps), h[d] = mu*g - bn_b
__global__ __launch_bounds__(256) void gemm_stats_kernel(
    const float* __restrict__ cap_mean, const float* __restrict__ fc_w,
    const float* __restrict__ rowsum, const float* __restrict__ rowss,
    const float* __restrict__ bn_w, const float* __restrict__ bn_b,
    float* __restrict__ Ppart, float* __restrict__ g, float* __restrict__ h) {
  __shared__ float As[32][64];  // [k][c], swizzled
  __shared__ float Bs[32][64];  // [k][n], swizzled
  __shared__ float s1[4][64], s2[4][64];
  int bid = blockIdx.x;
  int t = threadIdx.x;
  if (bid < 512) {
    int nt = bid & 31, ct = (bid >> 5) & 3, kz = bid >> 7;
    int tr = t >> 4, tc = t & 15;           // output: c-rows tr*4.., n-cols tc*4..
    int cs = t >> 2, k0 = (t & 3) << 3;     // staging: row cs, 8 k from k0
    const float* arow = cap_mean + (size_t)(ct * 64 + cs) * D_ + kz * 256;
    const float* brow = fc_w + (size_t)(nt * 64 + cs) * D_ + kz * 256;
    float acc[4][4] = {};
    int sa = SWZ64(k0, cs);
    for (int kb = 0; kb < 256; kb += 32) {
      float4 a0 = *(const float4*)&arow[kb + k0];
      float4 a1 = *(const float4*)&arow[kb + k0 + 4];
      float4 b0 = *(const float4*)&brow[kb + k0];
      float4 b1 = *(const float4*)&brow[kb + k0 + 4];
      __syncthreads();  // previous iter's readers done
      As[k0 + 0][sa] = a0.x; As[k0 + 1][sa] = a0.y; As[k0 + 2][sa] = a0.z; As[k0 + 3][sa] = a0.w;
      As[k0 + 4][sa] = a1.x; As[k0 + 5][sa] = a1.y; As[k0 + 6][sa] = a1.z; As[k0 + 7][sa] = a1.w;
      Bs[k0 + 0][sa] = b0.x; Bs[k0 + 1][sa] = b0.y; Bs[k0 + 2][sa] = b0.z; Bs[k0 + 3][sa] = b0.w;
      Bs[k0 + 4][sa] = b1.x; Bs[k0 + 5][sa] = b1.y; Bs[k0 + 6][sa] = b1.z; Bs[k0 + 7][sa] = b1.w;
      __syncthreads();
#pragma unroll
      for (int kk = 0; kk < 32; ++kk) {
        float4 av = *(const float4*)&As[kk][SWZ64(kk, tr * 4)];
        float4 bv = *(const float4*)&Bs[kk][SWZ64(kk, tc * 4)];
        acc[0][0] += av.x * bv.x; acc[0][1] += av.x * bv.y; acc[0][2] += av.x * bv.z; acc[0][3] += av.x * bv.w;
        acc[1][0] += av.y * bv.x; acc[1][1] += av.y * bv.y; acc[1][2] += av.y * bv.z; acc[1][3] += av.y * bv.w;
        acc[2][0] += av.z * bv.x; acc[2][1] += av.z * bv.y; acc[2][2] += av.z * bv.z; acc[2][3] += av.z * bv.w;
        acc[3][0] += av.w * bv.x; acc[3][1] += av.w * bv.y; acc[3][2] += av.w * bv.z; acc[3][3] += av.w * bv.w;
      }
    }
    int c = ct * 64 + tr * 4;
    int n = nt * 64 + tc * 4;
#pragma unroll
    for (int i = 0; i < 4; ++i) {
      *(float4*)&Ppart[((size_t)kz * 256 + c + i) * 2048 + n] =
          make_float4(acc[i][0], acc[i][1], acc[i][2], acc[i][3]);
    }
  } else {
    int sb = bid - 512;
    int dl = t & 63;
    int d = sb * 64 + dl;
    int bg = t >> 6;
    float cs = 0.0f, c2 = 0.0f;
    for (int b = bg * 64; b < bg * 64 + 64; ++b) {
      cs += rowsum[(size_t)b * D_ + d];
      c2 += rowss[(size_t)b * D_ + d];
    }
    s1[bg][dl] = cs;
    s2[bg][dl] = c2;
    __syncthreads();
    if (t < 64) {
      cs = s1[0][dl] + s1[1][dl] + s1[2][dl] + s1[3][dl];
      c2 = s2[0][dl] + s2[1][dl] + s2[2][dl] + s2[3][dl];
      const float inv = 1.0f / (float)(B_ * R_);
      float m = cs * inv, ex2 = c2 * inv;
      float var = ex2 - m * m;
      float gg = bn_w[d] / sqrtf(var + 1e-5f);
      g[d] = gg;
      h[d] = m * gg - bn_b[d];
    }
  }
}

// ---- fused: reduce split-K partials + fc_b -> params; per-c scalars ----
// grid 256 (one c per block); thread t owns n-cols [8t, 8t+8)
__global__ __launch_bounds__(256) void reduce_scal_kernel(const float* __restrict__ Ppart,
    const float* __restrict__ fc_b, const float* __restrict__ cap_mean,
    float* __restrict__ params, float* __restrict__ rawC, float* __restrict__ BBc,
    float* __restrict__ rn) {
  __shared__ float sred[4], sred2[4], sred3[4];
  int c = blockIdx.x, t = threadIdx.x;
  float4 p0 = reinterpret_cast<const float4*>(fc_b)[2 * t];
  float4 p1 = reinterpret_cast<const float4*>(fc_b)[2 * t + 1];
#pragma unroll
  for (int kz = 0; kz < 4; ++kz) {
    size_t base4 = ((size_t)kz * 256 + c) * 512;
    float4 q0 = reinterpret_cast<const float4*>(Ppart)[base4 + 2 * t];
    float4 q1 = reinterpret_cast<const float4*>(Ppart)[base4 + 2 * t + 1];
    p0.x += q0.x; p0.y += q0.y; p0.z += q0.z; p0.w += q0.w;
    p1.x += q1.x; p1.y += q1.y; p1.z += q1.z; p1.w += q1.w;
  }
  reinterpret_cast<float4*>(params)[(size_t)c * 512 + 2 * t] = p0;
  reinterpret_cast<float4*>(params)[(size_t)c * 512 + 2 * t + 1] = p1;
  float4 cm = reinterpret_cast<const float4*>(cap_mean)[(size_t)c * 256 + t];
  float sBc = p0.y * cm.x + p0.w * cm.y + p1.y * cm.z + p1.w * cm.w;
  float sB2 = p0.y * p0.y + p0.w * p0.w + p1.y * p1.y + p1.w * p1.w;
  float scm = cm.x * cm.x + cm.y * cm.y + cm.z * cm.z + cm.w * cm.w;
  float a = block_sum(sBc, sred);
  float bsum = block_sum(sB2, sred2);
  float cq = block_sum(scm, sred3);
  if (t == 0) {
    rawC[c] = a;
    BBc[c] = bsum;
    rn[c] = 1.0f / (sqrtf(cq) + 1e-8f);
  }
}

// ---- fused 3-GEMM for sims numerator/denominator, split-K=16 ----
// grid (8 bt, 4 ct, 16 kz); tile 32b x 64c, K-chunk 64; base computed on the fly
__global__ __launch_bounds__(256) void sims_kernel(const float* __restrict__ rowsum,
    const float* __restrict__ g, const float* __restrict__ h,
    const float* __restrict__ params, const float* __restrict__ cap_mean,
    float* __restrict__ Npart, float* __restrict__ Qpart) {
  __shared__ float Tb[64][32];
  __shared__ float Tacv[64][64];
  __shared__ float Ta2[64][64];
  __shared__ float Tab[64][64];
  int t = threadIdx.x;
  int bt = blockIdx.x, ct = blockIdx.y, kz = blockIdx.z;
  int k0 = kz * 64;
  int tr = t >> 4, tc = t & 15;
  int bb = t >> 3, kb = (t & 7) << 3;   // Tb staging
  int cc = t >> 2, dc = (t & 3) << 4;   // T* staging
  const float* prow = params + (size_t)(ct * 64 + cc) * 2048 + 2 * k0;
  const float* cmrow = cap_mean + (size_t)(ct * 64 + cc) * 1024 + k0;
  const float* rsrow = rowsum + (size_t)(bt * 32 + bb) * 1024 + k0;
  const float invR = 1.0f / (float)R_;
  // stage Tb[k][b] = base (transposed, swizzled): base = rs*invR*g - h
  {
    float4 v0 = *(const float4*)&rsrow[kb];
    float4 v1 = *(const float4*)&rsrow[kb + 4];
    float4 g0 = *(const float4*)&g[k0 + kb];
    float4 g1 = *(const float4*)&g[k0 + kb + 4];
    float4 h0 = *(const float4*)&h[k0 + kb];
    float4 h1 = *(const float4*)&h[k0 + kb + 4];
    int sb = SWZ32(kb, bb);
    Tb[kb + 0][sb] = v0.x * invR * g0.x - h0.x;
    Tb[kb + 1][sb] = v0.y * invR * g0.y - h0.y;
    Tb[kb + 2][sb] = v0.z * invR * g0.z - h0.z;
    Tb[kb + 3][sb] = v0.w * invR * g0.w - h0.w;
    Tb[kb + 4][sb] = v1.x * invR * g1.x - h1.x;
    Tb[kb + 5][sb] = v1.y * invR * g1.y - h1.y;
    Tb[kb + 6][sb] = v1.z * invR * g1.z - h1.z;
    Tb[kb + 7][sb] = v1.w * invR * g1.w - h1.w;
  }
  // stage Tacv/Ta2/Tab [d][c] (swizzled); rn folded into final kernel
  int sc = SWZ64(dc, cc);
#pragma unroll
  for (int j = 0; j < 16; j += 4) {
    int d = dc + j;
    float4 p0 = *(const float4*)&prow[2 * d];
    float4 p1 = *(const float4*)&prow[2 * d + 4];
    float4 cm = *(const float4*)&cmrow[d];
    Tacv[d + 0][sc] = p0.x * cm.x; Ta2[d + 0][sc] = p0.x * p0.x; Tab[d + 0][sc] = 2.f * p0.x * p0.y;
    Tacv[d + 1][sc] = p0.z * cm.y; Ta2[d + 1][sc] = p0.z * p0.z; Tab[d + 1][sc] = 2.f * p0.z * p0.w;
    Tacv[d + 2][sc] = p1.x * cm.z; Ta2[d + 2][sc] = p1.x * p1.x; Tab[d + 2][sc] = 2.f * p1.x * p1.y;
    Tacv[d + 3][sc] = p1.z * cm.w; Ta2[d + 3][sc] = p1.z * p1.z; Tab[d + 3][sc] = 2.f * p1.z * p1.w;
  }
  __syncthreads();
  float accN[2][4] = {};
  float accQ[2][4] = {};
#pragma unroll 8
  for (int kk = 0; kk < 64; ++kk) {
    float2 bv = *(const float2*)&Tb[kk][SWZ32(kk, tr * 2)];
    float4 acv = *(const float4*)&Tacv[kk][SWZ64(kk, tc * 4)];
    float4 a2v = *(const float4*)&Ta2[kk][SWZ64(kk, tc * 4)];
    float4 abv = *(const float4*)&Tab[kk][SWZ64(kk, tc * 4)];
    float b0 = bv.x, b1 = bv.y;
    float q0 = b0 * b0, q1 = b1 * b1;
    accN[0][0] += b0 * acv.x; accN[0][1] += b0 * acv.y; accN[0][2] += b0 * acv.z; accN[0][3] += b0 * acv.w;
    accN[1][0] += b1 * acv.x; accN[1][1] += b1 * acv.y; accN[1][2] += b1 * acv.z; accN[1][3] += b1 * acv.w;
    accQ[0][0] += q0 * a2v.x; accQ[0][1] += q0 * a2v.y; accQ[0][2] += q0 * a2v.z; accQ[0][3] += q0 * a2v.w;
    accQ[1][0] += q1 * a2v.x; accQ[1][1] += q1 * a2v.y; accQ[1][2] += q1 * a2v.z; accQ[1][3] += q1 * a2v.w;
    accQ[0][0] += b0 * abv.x; accQ[0][1] += b0 * abv.y; accQ[0][2] += b0 * abv.z; accQ[0][3] += b0 * abv.w;
    accQ[1][0] += b1 * abv.x; accQ[1][1] += b1 * abv.y; accQ[1][2] += b1 * abv.z; accQ[1][3] += b1 * abv.w;
  }
  int br = bt * 32 + tr * 2;
  int c = ct * 64 + tc * 4;
#pragma unroll
  for (int i = 0; i < 2; ++i) {
    size_t o = ((size_t)kz * 256 + br + i) * 256 + c;
    *(float4*)&Npart[o] = make_float4(accN[i][0], accN[i][1], accN[i][2], accN[i][3]);
    *(float4*)&Qpart[o] = make_float4(accQ[i][0], accQ[i][1], accQ[i][2], accQ[i][3]);
  }
}

// ---- combine split-K partials, apply per-c constants + rn, normalize ----
__global__ __launch_bounds__(256) void final_kernel(const float* __restrict__ Npart,
    const float* __restrict__ Qpart, const float* __restrict__ rawC,
    const float* __restrict__ BBc, const float* __restrict__ rn, float* __restrict__ out) {
  int b = blockIdx.x, c = threadIdx.x;
  float N = rawC[c], Q = BBc[c];
#pragma unroll
  for (int kz = 0; kz < 16; ++kz) {
    size_t o = ((size_t)kz * 256 + b) * 256 + c;
    N += Npart[o];
    Q += Qpart[o];
  }
  out[b * 256 + c] = N * rn[c] / (sqrtf(Q) + 1e-8f);
}

extern "C" void kernel_launch(void* const* d_in, const int* in_sizes, int n_in,
                              void* d_out, int out_size, void* d_ws, size_t ws_size,
                              hipStream_t stream) {
  const float* img = (const float*)d_in[0];
  const float* cap = (const float*)d_in[1];
  const int* lens = (const int*)d_in[2];
  const float* fc_w = (const float*)d_in[3];
  const float* fc_b = (const float*)d_in[4];
  const float* bn_w = (const float*)d_in[5];
  const float* bn_b = (const float*)d_in[6];
  float* out = (float*)d_out;
  float* ws = (float*)d_ws;

  float* cap_mean = ws;                //  262144
  float* rowsum   = ws + 262144;       //  262144
  float* rowss    = ws + 524288;       //  262144
  float* g        = ws + 786432;       //    1024
  float* h        = ws + 787456;       //    1024
  float* params   = ws + 788480;       //  524288
  float* rawC     = ws + 1312768;      //     256
  float* BBc      = ws + 1313024;      //     256
  float* rn       = ws + 1313280;      //     256
  float* region   = ws + 1313536;      // 2097152 shared: Ppart then Npart/Qpart
  float* Ppart    = region;            // 4 * 524288
  float* Npart    = region;            // 16 * 65536
  float* Qpart    = region + 1048576;  // 16 * 65536   total ws ~13.6 MB

  input_kernel<<<1024, 256, 0, stream>>>(cap, img, lens, cap_mean, rowsum, rowss);
  gemm_stats_kernel<<<528, 256, 0, stream>>>(cap_mean, fc_w, rowsum, rowss,
                                             bn_w, bn_b, Ppart, g, h);
  reduce_scal_kernel<<<256, 256, 0, stream>>>(Ppart, fc_b, cap_mean, params,
                                              rawC, BBc, rn);
  sims_kernel<<<dim3(8, 4, 16), 256, 0, stream>>>(rowsum, g, h, params, cap_mean,
                                                  Npart, Qpart);
  final_kernel<<<256, 256, 0, stream>>>(Npart, Qpart, rawC, BBc, rn, out);
}